// Round 15
// baseline (159.416 us; speedup 1.0000x reference)
//
#include <hip/hip_runtime.h>
#include <hip/hip_bf16.h>

// MSTAGNN: N=10000, E=160000, HID=64, HEADS=8, D=8, KHOPS=3.
// R15: (1) deg_kernel + base_kernel fused into degscan_kernel using the
// last-done-block ticket pattern (grid-stride edge atomics -> threadfence ->
// ticket -> last block does the full 1024-thread serial scan). Scan is now
// globally monotone, atomic base counter gone. 7 -> 6 dispatches.
// (2) kjn written with non-temporal stores (write-once read-next-kernel;
// keeps L2 for K rows / Vb / M rows). Everything else = R14 (best, 121.4us):
// erec int2 {j, norm_bits}; kjn = norm*relu(K[row]+ef) bf16 streamed by
// hop0; Vb bf16 table (1.28MB, L2) gathered per edge; M bf16 rows, one
// wave/node, f32 accum; qkv 4 nodes/thread (8 hits the VGPR cliff, R13).
// No memsets. K-propagation in the reference is dead code.

#define HIDC 64
#define MELEMS 512  // HEADS * D * D

typedef float fx4 __attribute__((ext_vector_type(4)));
typedef unsigned ux2 __attribute__((ext_vector_type(2)));

__device__ __forceinline__ unsigned bf16rne(float x) {
    unsigned u = __float_as_uint(x);
    return (u + 0x7FFFu + ((u >> 16) & 1u)) >> 16;
}
__device__ __forceinline__ unsigned pack2(float lo, float hi) {
    return bf16rne(lo) | (bf16rne(hi) << 16);
}
__device__ __forceinline__ float bfval(unsigned short v) {
    return __uint_as_float((unsigned)v << 16);
}
__device__ __forceinline__ void acc8(float* acc, float s, uint4 a) {
    acc[0] = fmaf(s, __uint_as_float(a.x << 16), acc[0]);
    acc[1] = fmaf(s, __uint_as_float(a.x & 0xFFFF0000u), acc[1]);
    acc[2] = fmaf(s, __uint_as_float(a.y << 16), acc[2]);
    acc[3] = fmaf(s, __uint_as_float(a.y & 0xFFFF0000u), acc[3]);
    acc[4] = fmaf(s, __uint_as_float(a.z << 16), acc[4]);
    acc[5] = fmaf(s, __uint_as_float(a.z & 0xFFFF0000u), acc[5]);
    acc[6] = fmaf(s, __uint_as_float(a.w << 16), acc[6]);
    acc[7] = fmaf(s, __uint_as_float(a.w & 0xFFFF0000u), acc[7]);
}

// Q,K = x@W + b (relu on Q); Vb = bf16(x@Wv+bv); out = hopwise[0]*V (full
// overwrite -> replay safe). 4 nodes/thread (VGPR ~100; 8/thread hits the
// 256-VGPR cliff, R13). Side jobs: zero deg[] and the ticket counter.
__global__ __launch_bounds__(256) void qkv_kernel(
    const float* __restrict__ x,
    const float* __restrict__ Wq, const float* __restrict__ bq,
    const float* __restrict__ Wk, const float* __restrict__ bk,
    const float* __restrict__ Wv, const float* __restrict__ bv,
    const float* __restrict__ hopwise,
    float* __restrict__ Q, float* __restrict__ K,
    unsigned short* __restrict__ Vb,
    float* __restrict__ out, int* __restrict__ deg,
    int* __restrict__ done, int n) {
    int gid = blockIdx.x * blockDim.x + threadIdx.x;
    if (gid < n) deg[gid] = 0;
    if (gid == 0) *done = 0;
    int c = gid & 63;
    int nb = (gid >> 6) * 4;
    if (nb >= n) return;
    int mcnt = min(4, n - nb);
    float aq[4], ak[4], av[4];
    #pragma unroll
    for (int m = 0; m < 4; ++m) { aq[m] = bq[c]; ak[m] = bk[c]; av[m] = bv[c]; }
    const float4* x4 = (const float4*)x;
    for (int k4 = 0; k4 < 16; ++k4) {
        float4 xv[4];
        #pragma unroll
        for (int m = 0; m < 4; ++m)
            xv[m] = x4[(size_t)(nb + (m < mcnt ? m : 0)) * 16 + k4];
        #pragma unroll
        for (int kk = 0; kk < 4; ++kk) {
            int k = k4 * 4 + kk;
            float wq = Wq[k * HIDC + c], wk = Wk[k * HIDC + c], wv = Wv[k * HIDC + c];
            #pragma unroll
            for (int m = 0; m < 4; ++m) {
                float xvk = (kk == 0) ? xv[m].x : (kk == 1) ? xv[m].y
                          : (kk == 2) ? xv[m].z : xv[m].w;
                aq[m] = fmaf(xvk, wq, aq[m]);
                ak[m] = fmaf(xvk, wk, ak[m]);
                av[m] = fmaf(xvk, wv, av[m]);
            }
        }
    }
    #pragma unroll
    for (int m = 0; m < 4; ++m) {
        if (m < mcnt) {
            size_t idx = (size_t)(nb + m) * HIDC + c;
            Q[idx] = fmaxf(aq[m], 0.f);
            K[idx] = ak[m];
            Vb[idx] = (unsigned short)bf16rne(av[m]);
            out[idx] = hopwise[0] * av[m];
        }
    }
}

// fused degree histogram + exclusive scan (last-done-block pattern).
// Phase 1: grid-stride atomicAdd over edges. Phase 2 (last block only):
// full serial scan of deg[0..n) with 1024 threads -> rowbeg/cursor
// (globally monotone; no base counter needed). deg re-read via device-scope
// atomic loads to dodge cross-XCD cache staleness.
__global__ __launch_bounds__(1024) void degscan_kernel(
    const int* __restrict__ col, int* __restrict__ deg, int* __restrict__ done,
    int* __restrict__ rowbeg, int* __restrict__ cursor, int n, int e) {
    for (int i = blockIdx.x * 1024 + threadIdx.x; i < e; i += gridDim.x * 1024)
        atomicAdd(&deg[col[i]], 1);
    __threadfence();
    __shared__ int isLast;
    if (threadIdx.x == 0)
        isLast = (atomicAdd(done, 1) == (int)gridDim.x - 1);
    __syncthreads();
    if (!isLast) return;

    __shared__ int wsum[16];
    __shared__ int carry;
    int tid = threadIdx.x;
    int lane = tid & 63, w = tid >> 6;
    if (tid == 0) carry = 0;
    __syncthreads();
    for (int start = 0; start < n; start += 1024) {
        int i = start + tid;
        int v = (i < n)
            ? __hip_atomic_load(&deg[i], __ATOMIC_RELAXED, __HIP_MEMORY_SCOPE_AGENT)
            : 0;
        int s = v;
        #pragma unroll
        for (int off = 1; off < 64; off <<= 1) {
            int t = __shfl_up(s, off);
            if (lane >= off) s += t;
        }
        if (lane == 63) wsum[w] = s;
        __syncthreads();
        if (tid == 0) {
            int acc = carry;
            #pragma unroll
            for (int w2 = 0; w2 < 16; ++w2) { int t = wsum[w2]; wsum[w2] = acc; acc += t; }
            carry = acc;
        }
        __syncthreads();
        int excl = wsum[w] + s - v;
        if (i < n) {
            rowbeg[i] = excl;
            cursor[i] = excl;
        }
        __syncthreads();
    }
}

// fused pos+stage: 16 threads/edge. Leader (c4==0) computes norm + CSR slot
// (atomic), writes erec[pos]={srcrow, norm_bits}, broadcasts {r,pos,nv};
// all 16 lanes stage kjn[pos] = nv*relu(K[r]+ef[i]) as 64 bf16 (128B row).
// ef read non-temporal (read-once); kjn stored non-temporal (write-once,
// consumed sequentially next kernel) -> L2 kept for K rows.
__global__ __launch_bounds__(256) void stage_kernel(
    const int* __restrict__ row, const int* __restrict__ col,
    const float* __restrict__ ew, const int* __restrict__ deg,
    int* __restrict__ cursor, int2* __restrict__ erec,
    const float* __restrict__ K, const float* __restrict__ ef,
    unsigned short* __restrict__ kjn, int e) {
    int gtid = blockIdx.x * blockDim.x + threadIdx.x;
    int i = gtid >> 4;
    if (i >= e) return;
    int c4 = gtid & 15;
    int lane = threadIdx.x & 63;
    int lb = lane & 48;  // leader lane of this 16-thread group
    int r = 0, pos = 0;
    float nv = 0.f;
    if (c4 == 0) {
        r = row[i];
        int cc = col[i];
        int dr = deg[r], dc = deg[cc];
        nv = ew[i];
        nv *= (dr > 0) ? rsqrtf((float)dr) : 0.f;
        nv *= (dc > 0) ? rsqrtf((float)dc) : 0.f;
        pos = atomicAdd(&cursor[cc], 1);
        erec[pos] = make_int2(r, __float_as_int(nv));
    }
    r = __shfl(r, lb);
    pos = __shfl(pos, lb);
    nv = __shfl(nv, lb);
    const fx4* efv = (const fx4*)ef;
    const float4* Kv = (const float4*)K;
    fx4 f = __builtin_nontemporal_load(&efv[(size_t)i * 16 + c4]);
    float4 kk = Kv[(size_t)r * 16 + c4];
    ux2 kjp;
    kjp.x = pack2(nv * fmaxf(kk.x + f.x, 0.f), nv * fmaxf(kk.y + f.y, 0.f));
    kjp.y = pack2(nv * fmaxf(kk.z + f.z, 0.f), nv * fmaxf(kk.w + f.w, 0.f));
    __builtin_nontemporal_store(kjp, (ux2*)(kjn + (size_t)pos * 64) + c4);
}

// epilogue (64 threads/node, t = h*8+ii owns M[h][ii][0..7]):
// H = Q.M (reduce ii via xor 1/2/4), clamp-norm (j-reduce in-thread)
__device__ __forceinline__ void epilogue64(const float* acc, const float* __restrict__ Q,
                                           float hw, int n, int h, int ii,
                                           float* __restrict__ out) {
    float q = Q[n * HIDC + h * 8 + ii];
    float p[8];
    #pragma unroll
    for (int j = 0; j < 8; ++j) p[j] = q * acc[j];
    #pragma unroll
    for (int off = 1; off < 8; off <<= 1) {
        #pragma unroll
        for (int j = 0; j < 8; ++j) p[j] += __shfl_xor(p[j], off);
    }
    float ssq = 0.f;
    #pragma unroll
    for (int j = 0; j < 8; ++j) ssq = fmaf(p[j], p[j], ssq);
    float nr = sqrtf(ssq * 0.125f);
    float sc = (nr > 1.f) ? (hw / nr) : hw;
    if (ii == 0) {
        float4* o = (float4*)(out + (size_t)n * HIDC + h * 8);
        float4 c0 = o[0], c1 = o[1];
        c0.x = fmaf(p[0], sc, c0.x); c0.y = fmaf(p[1], sc, c0.y);
        c0.z = fmaf(p[2], sc, c0.z); c0.w = fmaf(p[3], sc, c0.w);
        c1.x = fmaf(p[4], sc, c1.x); c1.y = fmaf(p[5], sc, c1.y);
        c1.z = fmaf(p[6], sc, c1.z); c1.w = fmaf(p[7], sc, c1.w);
        o[0] = c0; o[1] = c1;
    }
}

// hop 0: one wave per node; kjn streamed sequentially (non-temporal),
// V gathered from the 1.28MB L2-resident bf16 table. Unroll 4.
__global__ __launch_bounds__(256) void hop0_kernel(
    const int* __restrict__ rowbeg, const int* __restrict__ deg,
    const int2* __restrict__ erec, const unsigned short* __restrict__ kjn,
    const unsigned short* __restrict__ Vb,
    const float* __restrict__ Q, const float* __restrict__ hopwise,
    unsigned short* __restrict__ M0, float* __restrict__ out, int nn) {
    int n = blockIdx.x * 4 + (threadIdx.x >> 6);
    if (n >= nn) return;
    int t = threadIdx.x & 63;
    int h = t >> 3, ii = t & 7;
    int beg = rowbeg[n], end = beg + deg[n];
    float acc[8] = {0, 0, 0, 0, 0, 0, 0, 0};
    int k = beg;
    for (; k + 4 <= end; k += 4) {
        int j0 = erec[k].x,     j1 = erec[k + 1].x;
        int j2 = erec[k + 2].x, j3 = erec[k + 3].x;
        float s0 = bfval(__builtin_nontemporal_load(&kjn[(size_t)(k)     * 64 + t]));
        float s1 = bfval(__builtin_nontemporal_load(&kjn[(size_t)(k + 1) * 64 + t]));
        float s2 = bfval(__builtin_nontemporal_load(&kjn[(size_t)(k + 2) * 64 + t]));
        float s3 = bfval(__builtin_nontemporal_load(&kjn[(size_t)(k + 3) * 64 + t]));
        uint4 v0 = *(const uint4*)(Vb + (size_t)j0 * 64 + h * 8);
        uint4 v1 = *(const uint4*)(Vb + (size_t)j1 * 64 + h * 8);
        uint4 v2 = *(const uint4*)(Vb + (size_t)j2 * 64 + h * 8);
        uint4 v3 = *(const uint4*)(Vb + (size_t)j3 * 64 + h * 8);
        acc8(acc, s0, v0);
        acc8(acc, s1, v1);
        acc8(acc, s2, v2);
        acc8(acc, s3, v3);
    }
    for (; k < end; ++k) {
        float s = bfval(__builtin_nontemporal_load(&kjn[(size_t)k * 64 + t]));
        uint4 v = *(const uint4*)(Vb + (size_t)erec[k].x * 64 + h * 8);
        acc8(acc, s, v);
    }
    uint4 st;
    st.x = pack2(acc[0], acc[1]); st.y = pack2(acc[2], acc[3]);
    st.z = pack2(acc[4], acc[5]); st.w = pack2(acc[6], acc[7]);
    ((uint4*)M0)[(size_t)n * 64 + t] = st;
    epilogue64(acc, Q, hopwise[1], n, h, ii, out);
}

// hop k>=1: Mout[n] = sum_e norm * Min[row[e]]; one wave per node, bf16 rows,
// unroll 8 (8 uint4 row-gathers in flight).
__global__ __launch_bounds__(256) void hopk_kernel(
    const int* __restrict__ rowbeg, const int* __restrict__ deg,
    const int2* __restrict__ erec,
    const unsigned short* __restrict__ Min, const float* __restrict__ Q,
    const float* __restrict__ hopwise, int hopidx,
    unsigned short* __restrict__ Mout, int writeM, float* __restrict__ out, int nn) {
    int n = blockIdx.x * 4 + (threadIdx.x >> 6);
    if (n >= nn) return;
    int t = threadIdx.x & 63;
    int beg = rowbeg[n], end = beg + deg[n];
    float acc[8] = {0, 0, 0, 0, 0, 0, 0, 0};
    const uint4* Mv = (const uint4*)Min;  // row j at Mv[j*64 + t]
    int k = beg;
    for (; k + 8 <= end; k += 8) {
        int2 e0 = erec[k],     e1 = erec[k + 1], e2 = erec[k + 2], e3 = erec[k + 3];
        int2 e4 = erec[k + 4], e5 = erec[k + 5], e6 = erec[k + 6], e7 = erec[k + 7];
        uint4 a0 = Mv[(size_t)e0.x * 64 + t];
        uint4 a1 = Mv[(size_t)e1.x * 64 + t];
        uint4 a2 = Mv[(size_t)e2.x * 64 + t];
        uint4 a3 = Mv[(size_t)e3.x * 64 + t];
        uint4 a4 = Mv[(size_t)e4.x * 64 + t];
        uint4 a5 = Mv[(size_t)e5.x * 64 + t];
        uint4 a6 = Mv[(size_t)e6.x * 64 + t];
        uint4 a7 = Mv[(size_t)e7.x * 64 + t];
        acc8(acc, __int_as_float(e0.y), a0);
        acc8(acc, __int_as_float(e1.y), a1);
        acc8(acc, __int_as_float(e2.y), a2);
        acc8(acc, __int_as_float(e3.y), a3);
        acc8(acc, __int_as_float(e4.y), a4);
        acc8(acc, __int_as_float(e5.y), a5);
        acc8(acc, __int_as_float(e6.y), a6);
        acc8(acc, __int_as_float(e7.y), a7);
    }
    for (; k + 4 <= end; k += 4) {
        int2 e0 = erec[k], e1 = erec[k + 1], e2 = erec[k + 2], e3 = erec[k + 3];
        uint4 a0 = Mv[(size_t)e0.x * 64 + t];
        uint4 a1 = Mv[(size_t)e1.x * 64 + t];
        uint4 a2 = Mv[(size_t)e2.x * 64 + t];
        uint4 a3 = Mv[(size_t)e3.x * 64 + t];
        acc8(acc, __int_as_float(e0.y), a0);
        acc8(acc, __int_as_float(e1.y), a1);
        acc8(acc, __int_as_float(e2.y), a2);
        acc8(acc, __int_as_float(e3.y), a3);
    }
    for (; k < end; ++k) {
        int2 e0 = erec[k];
        acc8(acc, __int_as_float(e0.y), Mv[(size_t)e0.x * 64 + t]);
    }
    if (writeM) {
        uint4 st;
        st.x = pack2(acc[0], acc[1]); st.y = pack2(acc[2], acc[3]);
        st.z = pack2(acc[4], acc[5]); st.w = pack2(acc[6], acc[7]);
        ((uint4*)Mout)[(size_t)n * 64 + t] = st;
    }
    int h = t >> 3, ii = t & 7;
    epilogue64(acc, Q, hopwise[hopidx], n, h, ii, out);
}

extern "C" void kernel_launch(void* const* d_in, const int* in_sizes, int n_in,
                              void* d_out, int out_size, void* d_ws, size_t ws_size,
                              hipStream_t stream) {
    const float* x       = (const float*)d_in[0];
    const int*   ei      = (const int*)d_in[1];
    const float* ef      = (const float*)d_in[2];
    const float* ew      = (const float*)d_in[3];
    const float* Wq      = (const float*)d_in[4];
    const float* bq      = (const float*)d_in[5];
    const float* Wk      = (const float*)d_in[6];
    const float* bk      = (const float*)d_in[7];
    const float* Wv      = (const float*)d_in[8];
    const float* bv      = (const float*)d_in[9];
    const float* hopwise = (const float*)d_in[10];
    float* out = (float*)d_out;

    const int n = in_sizes[0] / HIDC;   // 10000
    const int e = in_sizes[1] / 2;      // 160000
    const int* row = ei;
    const int* col = ei + e;

    char* base = (char*)d_ws;
    size_t off = 0;
    auto alloc = [&](size_t bytes) -> void* {
        void* p = base + off;
        off = (off + bytes + 255) & ~(size_t)255;
        return p;
    };
    int*            deg     = (int*)           alloc((size_t)n * 4);
    int*            cursor  = (int*)           alloc((size_t)n * 4);
    int*            rowbeg  = (int*)           alloc((size_t)n * 4);
    int*            done    = (int*)           alloc(256);
    int2*           erec    = (int2*)          alloc((size_t)e * 8);
    unsigned short* kjn     = (unsigned short*)alloc((size_t)e * HIDC * 2);
    float*          Q       = (float*)         alloc((size_t)n * HIDC * 4);
    float*          K       = (float*)         alloc((size_t)n * HIDC * 4);
    unsigned short* Vb      = (unsigned short*)alloc((size_t)n * HIDC * 2);
    unsigned short* M0      = (unsigned short*)alloc((size_t)n * MELEMS * 2);
    unsigned short* M1      = (unsigned short*)alloc((size_t)n * MELEMS * 2);
    (void)ws_size;

    // 4 nodes/thread-column: (n/4) waves of 64
    int qthreads = ((n + 3) / 4) * 64;
    int qb = (qthreads + 255) / 256;
    qkv_kernel<<<qb, 256, 0, stream>>>(x, Wq, bq, Wk, bk, Wv, bv, hopwise,
                                       Q, K, Vb, out, deg, done, n);

    int db = (e + 1023) / 1024;
    degscan_kernel<<<db, 1024, 0, stream>>>(col, deg, done, rowbeg, cursor, n, e);

    int sb = ((e * 16) + 255) / 256;
    stage_kernel<<<sb, 256, 0, stream>>>(row, col, ew, deg, cursor,
                                         erec, K, ef, kjn, e);

    int nb = (n + 3) / 4;
    hop0_kernel<<<nb, 256, 0, stream>>>(rowbeg, deg, erec, kjn, Vb, Q,
                                        hopwise, M0, out, n);
    hopk_kernel<<<nb, 256, 0, stream>>>(rowbeg, deg, erec, M0, Q, hopwise, 2, M1, 1, out, n);
    hopk_kernel<<<nb, 256, 0, stream>>>(rowbeg, deg, erec, M1, Q, hopwise, 3, M0, 0, out, n);
}

// Round 16
// 126.220 us; speedup vs baseline: 1.2630x; 1.2630x over previous
//
#include <hip/hip_runtime.h>
#include <hip/hip_bf16.h>

// MSTAGNN: N=10000, E=160000, HID=64, HEADS=8, D=8, KHOPS=3.
// R16 = R14 (best, 121.4us) + non-temporal kjn store kept from R15.
// R15 lesson: fusing deg+scan via last-done-block ticket cost 49us (device
// threadfence across 8 XCDs for 160k threads + serial tail) vs ~6us for the
// two separate launches. Reverted. Structure: erec int2 {j, norm_bits};
// kjn = norm*relu(K[row]+ef) bf16 streamed by hop0 (nt load); Vb bf16 table
// (1.28MB, L2) gathered per edge; M bf16 rows, one wave/node, f32 accum;
// qkv 4 nodes/thread (8 hits the VGPR cliff, R13). Parallel CSR base alloc.
// No memsets. K-propagation in the reference is dead code.

#define HIDC 64
#define MELEMS 512  // HEADS * D * D

typedef float fx4 __attribute__((ext_vector_type(4)));
typedef unsigned ux2 __attribute__((ext_vector_type(2)));

__device__ __forceinline__ unsigned bf16rne(float x) {
    unsigned u = __float_as_uint(x);
    return (u + 0x7FFFu + ((u >> 16) & 1u)) >> 16;
}
__device__ __forceinline__ unsigned pack2(float lo, float hi) {
    return bf16rne(lo) | (bf16rne(hi) << 16);
}
__device__ __forceinline__ float bfval(unsigned short v) {
    return __uint_as_float((unsigned)v << 16);
}
__device__ __forceinline__ void acc8(float* acc, float s, uint4 a) {
    acc[0] = fmaf(s, __uint_as_float(a.x << 16), acc[0]);
    acc[1] = fmaf(s, __uint_as_float(a.x & 0xFFFF0000u), acc[1]);
    acc[2] = fmaf(s, __uint_as_float(a.y << 16), acc[2]);
    acc[3] = fmaf(s, __uint_as_float(a.y & 0xFFFF0000u), acc[3]);
    acc[4] = fmaf(s, __uint_as_float(a.z << 16), acc[4]);
    acc[5] = fmaf(s, __uint_as_float(a.z & 0xFFFF0000u), acc[5]);
    acc[6] = fmaf(s, __uint_as_float(a.w << 16), acc[6]);
    acc[7] = fmaf(s, __uint_as_float(a.w & 0xFFFF0000u), acc[7]);
}

// Q,K = x@W + b (relu on Q); Vb = bf16(x@Wv+bv); out = hopwise[0]*V (full
// overwrite -> replay safe). 4 nodes/thread (VGPR ~100, good occupancy).
// Side jobs: zero deg[] and the CSR base counter.
__global__ __launch_bounds__(256) void qkv_kernel(
    const float* __restrict__ x,
    const float* __restrict__ Wq, const float* __restrict__ bq,
    const float* __restrict__ Wk, const float* __restrict__ bk,
    const float* __restrict__ Wv, const float* __restrict__ bv,
    const float* __restrict__ hopwise,
    float* __restrict__ Q, float* __restrict__ K,
    unsigned short* __restrict__ Vb,
    float* __restrict__ out, int* __restrict__ deg,
    int* __restrict__ counter, int n) {
    int gid = blockIdx.x * blockDim.x + threadIdx.x;
    if (gid < n) deg[gid] = 0;
    if (gid == 0) *counter = 0;
    int c = gid & 63;
    int nb = (gid >> 6) * 4;
    if (nb >= n) return;
    int mcnt = min(4, n - nb);
    float aq[4], ak[4], av[4];
    #pragma unroll
    for (int m = 0; m < 4; ++m) { aq[m] = bq[c]; ak[m] = bk[c]; av[m] = bv[c]; }
    const float4* x4 = (const float4*)x;
    for (int k4 = 0; k4 < 16; ++k4) {
        float4 xv[4];
        #pragma unroll
        for (int m = 0; m < 4; ++m)
            xv[m] = x4[(size_t)(nb + (m < mcnt ? m : 0)) * 16 + k4];
        #pragma unroll
        for (int kk = 0; kk < 4; ++kk) {
            int k = k4 * 4 + kk;
            float wq = Wq[k * HIDC + c], wk = Wk[k * HIDC + c], wv = Wv[k * HIDC + c];
            #pragma unroll
            for (int m = 0; m < 4; ++m) {
                float xvk = (kk == 0) ? xv[m].x : (kk == 1) ? xv[m].y
                          : (kk == 2) ? xv[m].z : xv[m].w;
                aq[m] = fmaf(xvk, wq, aq[m]);
                ak[m] = fmaf(xvk, wk, ak[m]);
                av[m] = fmaf(xvk, wv, av[m]);
            }
        }
    }
    #pragma unroll
    for (int m = 0; m < 4; ++m) {
        if (m < mcnt) {
            size_t idx = (size_t)(nb + m) * HIDC + c;
            Q[idx] = fmaxf(aq[m], 0.f);
            K[idx] = ak[m];
            Vb[idx] = (unsigned short)bf16rne(av[m]);
            out[idx] = hopwise[0] * av[m];
        }
    }
}

__global__ void deg_kernel(const int* __restrict__ col, int* __restrict__ deg, int e) {
    int i = blockIdx.x * blockDim.x + threadIdx.x;
    if (i < e) atomicAdd(&deg[col[i]], 1);
}

// parallel CSR base allocation: per-1024-node block scan + atomic block base.
// rowbeg[i] = cursor[i] = global slot base for node i (NOT globally monotone;
// hop kernels use end = rowbeg[n] + deg[n]).
__global__ __launch_bounds__(1024) void base_kernel(const int* __restrict__ deg,
                                                    int* __restrict__ counter,
                                                    int* __restrict__ rowbeg,
                                                    int* __restrict__ cursor, int n) {
    __shared__ int wsum[16];
    __shared__ int blockbase;
    int i = blockIdx.x * 1024 + threadIdx.x;
    int lane = threadIdx.x & 63, w = threadIdx.x >> 6;
    int v = (i < n) ? deg[i] : 0;
    int s = v;
    #pragma unroll
    for (int off = 1; off < 64; off <<= 1) {
        int t = __shfl_up(s, off);
        if (lane >= off) s += t;
    }
    if (lane == 63) wsum[w] = s;
    __syncthreads();
    if (threadIdx.x == 0) {
        int acc = 0;
        #pragma unroll
        for (int w2 = 0; w2 < 16; ++w2) { int t = wsum[w2]; wsum[w2] = acc; acc += t; }
        blockbase = atomicAdd(counter, acc);
    }
    __syncthreads();
    int excl = blockbase + wsum[w] + s - v;
    if (i < n) {
        rowbeg[i] = excl;
        cursor[i] = excl;
    }
}

// fused pos+stage: 16 threads/edge. Leader (c4==0) computes norm + CSR slot
// (atomic), writes erec[pos]={srcrow, norm_bits}, broadcasts {r,pos,nv};
// all 16 lanes stage kjn[pos] = nv*relu(K[r]+ef[i]) as 64 bf16 (128B row).
// ef read non-temporal (read-once); kjn stored non-temporal (write-once,
// consumed sequentially next kernel) -> L2 kept for K rows / Vb.
__global__ __launch_bounds__(256) void stage_kernel(
    const int* __restrict__ row, const int* __restrict__ col,
    const float* __restrict__ ew, const int* __restrict__ deg,
    int* __restrict__ cursor, int2* __restrict__ erec,
    const float* __restrict__ K, const float* __restrict__ ef,
    unsigned short* __restrict__ kjn, int e) {
    int gtid = blockIdx.x * blockDim.x + threadIdx.x;
    int i = gtid >> 4;
    if (i >= e) return;
    int c4 = gtid & 15;
    int lane = threadIdx.x & 63;
    int lb = lane & 48;  // leader lane of this 16-thread group
    int r = 0, pos = 0;
    float nv = 0.f;
    if (c4 == 0) {
        r = row[i];
        int cc = col[i];
        int dr = deg[r], dc = deg[cc];
        nv = ew[i];
        nv *= (dr > 0) ? rsqrtf((float)dr) : 0.f;
        nv *= (dc > 0) ? rsqrtf((float)dc) : 0.f;
        pos = atomicAdd(&cursor[cc], 1);
        erec[pos] = make_int2(r, __float_as_int(nv));
    }
    r = __shfl(r, lb);
    pos = __shfl(pos, lb);
    nv = __shfl(nv, lb);
    const fx4* efv = (const fx4*)ef;
    const float4* Kv = (const float4*)K;
    fx4 f = __builtin_nontemporal_load(&efv[(size_t)i * 16 + c4]);
    float4 kk = Kv[(size_t)r * 16 + c4];
    ux2 kjp;
    kjp.x = pack2(nv * fmaxf(kk.x + f.x, 0.f), nv * fmaxf(kk.y + f.y, 0.f));
    kjp.y = pack2(nv * fmaxf(kk.z + f.z, 0.f), nv * fmaxf(kk.w + f.w, 0.f));
    __builtin_nontemporal_store(kjp, (ux2*)(kjn + (size_t)pos * 64) + c4);
}

// epilogue (64 threads/node, t = h*8+ii owns M[h][ii][0..7]):
// H = Q.M (reduce ii via xor 1/2/4), clamp-norm (j-reduce in-thread)
__device__ __forceinline__ void epilogue64(const float* acc, const float* __restrict__ Q,
                                           float hw, int n, int h, int ii,
                                           float* __restrict__ out) {
    float q = Q[n * HIDC + h * 8 + ii];
    float p[8];
    #pragma unroll
    for (int j = 0; j < 8; ++j) p[j] = q * acc[j];
    #pragma unroll
    for (int off = 1; off < 8; off <<= 1) {
        #pragma unroll
        for (int j = 0; j < 8; ++j) p[j] += __shfl_xor(p[j], off);
    }
    float ssq = 0.f;
    #pragma unroll
    for (int j = 0; j < 8; ++j) ssq = fmaf(p[j], p[j], ssq);
    float nr = sqrtf(ssq * 0.125f);
    float sc = (nr > 1.f) ? (hw / nr) : hw;
    if (ii == 0) {
        float4* o = (float4*)(out + (size_t)n * HIDC + h * 8);
        float4 c0 = o[0], c1 = o[1];
        c0.x = fmaf(p[0], sc, c0.x); c0.y = fmaf(p[1], sc, c0.y);
        c0.z = fmaf(p[2], sc, c0.z); c0.w = fmaf(p[3], sc, c0.w);
        c1.x = fmaf(p[4], sc, c1.x); c1.y = fmaf(p[5], sc, c1.y);
        c1.z = fmaf(p[6], sc, c1.z); c1.w = fmaf(p[7], sc, c1.w);
        o[0] = c0; o[1] = c1;
    }
}

// hop 0: one wave per node; kjn streamed sequentially (non-temporal),
// V gathered from the 1.28MB L2-resident bf16 table. Unroll 4.
__global__ __launch_bounds__(256) void hop0_kernel(
    const int* __restrict__ rowbeg, const int* __restrict__ deg,
    const int2* __restrict__ erec, const unsigned short* __restrict__ kjn,
    const unsigned short* __restrict__ Vb,
    const float* __restrict__ Q, const float* __restrict__ hopwise,
    unsigned short* __restrict__ M0, float* __restrict__ out, int nn) {
    int n = blockIdx.x * 4 + (threadIdx.x >> 6);
    if (n >= nn) return;
    int t = threadIdx.x & 63;
    int h = t >> 3, ii = t & 7;
    int beg = rowbeg[n], end = beg + deg[n];
    float acc[8] = {0, 0, 0, 0, 0, 0, 0, 0};
    int k = beg;
    for (; k + 4 <= end; k += 4) {
        int j0 = erec[k].x,     j1 = erec[k + 1].x;
        int j2 = erec[k + 2].x, j3 = erec[k + 3].x;
        float s0 = bfval(__builtin_nontemporal_load(&kjn[(size_t)(k)     * 64 + t]));
        float s1 = bfval(__builtin_nontemporal_load(&kjn[(size_t)(k + 1) * 64 + t]));
        float s2 = bfval(__builtin_nontemporal_load(&kjn[(size_t)(k + 2) * 64 + t]));
        float s3 = bfval(__builtin_nontemporal_load(&kjn[(size_t)(k + 3) * 64 + t]));
        uint4 v0 = *(const uint4*)(Vb + (size_t)j0 * 64 + h * 8);
        uint4 v1 = *(const uint4*)(Vb + (size_t)j1 * 64 + h * 8);
        uint4 v2 = *(const uint4*)(Vb + (size_t)j2 * 64 + h * 8);
        uint4 v3 = *(const uint4*)(Vb + (size_t)j3 * 64 + h * 8);
        acc8(acc, s0, v0);
        acc8(acc, s1, v1);
        acc8(acc, s2, v2);
        acc8(acc, s3, v3);
    }
    for (; k < end; ++k) {
        float s = bfval(__builtin_nontemporal_load(&kjn[(size_t)k * 64 + t]));
        uint4 v = *(const uint4*)(Vb + (size_t)erec[k].x * 64 + h * 8);
        acc8(acc, s, v);
    }
    uint4 st;
    st.x = pack2(acc[0], acc[1]); st.y = pack2(acc[2], acc[3]);
    st.z = pack2(acc[4], acc[5]); st.w = pack2(acc[6], acc[7]);
    ((uint4*)M0)[(size_t)n * 64 + t] = st;
    epilogue64(acc, Q, hopwise[1], n, h, ii, out);
}

// hop k>=1: Mout[n] = sum_e norm * Min[row[e]]; one wave per node, bf16 rows,
// unroll 8 (8 uint4 row-gathers in flight).
__global__ __launch_bounds__(256) void hopk_kernel(
    const int* __restrict__ rowbeg, const int* __restrict__ deg,
    const int2* __restrict__ erec,
    const unsigned short* __restrict__ Min, const float* __restrict__ Q,
    const float* __restrict__ hopwise, int hopidx,
    unsigned short* __restrict__ Mout, int writeM, float* __restrict__ out, int nn) {
    int n = blockIdx.x * 4 + (threadIdx.x >> 6);
    if (n >= nn) return;
    int t = threadIdx.x & 63;
    int beg = rowbeg[n], end = beg + deg[n];
    float acc[8] = {0, 0, 0, 0, 0, 0, 0, 0};
    const uint4* Mv = (const uint4*)Min;  // row j at Mv[j*64 + t]
    int k = beg;
    for (; k + 8 <= end; k += 8) {
        int2 e0 = erec[k],     e1 = erec[k + 1], e2 = erec[k + 2], e3 = erec[k + 3];
        int2 e4 = erec[k + 4], e5 = erec[k + 5], e6 = erec[k + 6], e7 = erec[k + 7];
        uint4 a0 = Mv[(size_t)e0.x * 64 + t];
        uint4 a1 = Mv[(size_t)e1.x * 64 + t];
        uint4 a2 = Mv[(size_t)e2.x * 64 + t];
        uint4 a3 = Mv[(size_t)e3.x * 64 + t];
        uint4 a4 = Mv[(size_t)e4.x * 64 + t];
        uint4 a5 = Mv[(size_t)e5.x * 64 + t];
        uint4 a6 = Mv[(size_t)e6.x * 64 + t];
        uint4 a7 = Mv[(size_t)e7.x * 64 + t];
        acc8(acc, __int_as_float(e0.y), a0);
        acc8(acc, __int_as_float(e1.y), a1);
        acc8(acc, __int_as_float(e2.y), a2);
        acc8(acc, __int_as_float(e3.y), a3);
        acc8(acc, __int_as_float(e4.y), a4);
        acc8(acc, __int_as_float(e5.y), a5);
        acc8(acc, __int_as_float(e6.y), a6);
        acc8(acc, __int_as_float(e7.y), a7);
    }
    for (; k + 4 <= end; k += 4) {
        int2 e0 = erec[k], e1 = erec[k + 1], e2 = erec[k + 2], e3 = erec[k + 3];
        uint4 a0 = Mv[(size_t)e0.x * 64 + t];
        uint4 a1 = Mv[(size_t)e1.x * 64 + t];
        uint4 a2 = Mv[(size_t)e2.x * 64 + t];
        uint4 a3 = Mv[(size_t)e3.x * 64 + t];
        acc8(acc, __int_as_float(e0.y), a0);
        acc8(acc, __int_as_float(e1.y), a1);
        acc8(acc, __int_as_float(e2.y), a2);
        acc8(acc, __int_as_float(e3.y), a3);
    }
    for (; k < end; ++k) {
        int2 e0 = erec[k];
        acc8(acc, __int_as_float(e0.y), Mv[(size_t)e0.x * 64 + t]);
    }
    if (writeM) {
        uint4 st;
        st.x = pack2(acc[0], acc[1]); st.y = pack2(acc[2], acc[3]);
        st.z = pack2(acc[4], acc[5]); st.w = pack2(acc[6], acc[7]);
        ((uint4*)Mout)[(size_t)n * 64 + t] = st;
    }
    int h = t >> 3, ii = t & 7;
    epilogue64(acc, Q, hopwise[hopidx], n, h, ii, out);
}

extern "C" void kernel_launch(void* const* d_in, const int* in_sizes, int n_in,
                              void* d_out, int out_size, void* d_ws, size_t ws_size,
                              hipStream_t stream) {
    const float* x       = (const float*)d_in[0];
    const int*   ei      = (const int*)d_in[1];
    const float* ef      = (const float*)d_in[2];
    const float* ew      = (const float*)d_in[3];
    const float* Wq      = (const float*)d_in[4];
    const float* bq      = (const float*)d_in[5];
    const float* Wk      = (const float*)d_in[6];
    const float* bk      = (const float*)d_in[7];
    const float* Wv      = (const float*)d_in[8];
    const float* bv      = (const float*)d_in[9];
    const float* hopwise = (const float*)d_in[10];
    float* out = (float*)d_out;

    const int n = in_sizes[0] / HIDC;   // 10000
    const int e = in_sizes[1] / 2;      // 160000
    const int* row = ei;
    const int* col = ei + e;

    char* base = (char*)d_ws;
    size_t off = 0;
    auto alloc = [&](size_t bytes) -> void* {
        void* p = base + off;
        off = (off + bytes + 255) & ~(size_t)255;
        return p;
    };
    int*            deg     = (int*)           alloc((size_t)n * 4);
    int*            cursor  = (int*)           alloc((size_t)n * 4);
    int*            rowbeg  = (int*)           alloc((size_t)n * 4);
    int*            counter = (int*)           alloc(256);
    int2*           erec    = (int2*)          alloc((size_t)e * 8);
    unsigned short* kjn     = (unsigned short*)alloc((size_t)e * HIDC * 2);
    float*          Q       = (float*)         alloc((size_t)n * HIDC * 4);
    float*          K       = (float*)         alloc((size_t)n * HIDC * 4);
    unsigned short* Vb      = (unsigned short*)alloc((size_t)n * HIDC * 2);
    unsigned short* M0      = (unsigned short*)alloc((size_t)n * MELEMS * 2);
    unsigned short* M1      = (unsigned short*)alloc((size_t)n * MELEMS * 2);
    (void)ws_size;

    // 4 nodes/thread-column: (n/4) waves of 64
    int qthreads = ((n + 3) / 4) * 64;
    int qb = (qthreads + 255) / 256;
    qkv_kernel<<<qb, 256, 0, stream>>>(x, Wq, bq, Wk, bk, Wv, bv, hopwise,
                                       Q, K, Vb, out, deg, counter, n);

    int eb = (e + 255) / 256;
    deg_kernel<<<eb, 256, 0, stream>>>(col, deg, e);

    int bb = (n + 1023) / 1024;
    base_kernel<<<bb, 1024, 0, stream>>>(deg, counter, rowbeg, cursor, n);

    int sb = ((e * 16) + 255) / 256;
    stage_kernel<<<sb, 256, 0, stream>>>(row, col, ew, deg, cursor,
                                         erec, K, ef, kjn, e);

    int nb = (n + 3) / 4;
    hop0_kernel<<<nb, 256, 0, stream>>>(rowbeg, deg, erec, kjn, Vb, Q,
                                        hopwise, M0, out, n);
    hopk_kernel<<<nb, 256, 0, stream>>>(rowbeg, deg, erec, M0, Q, hopwise, 2, M1, 1, out, n);
    hopk_kernel<<<nb, 256, 0, stream>>>(rowbeg, deg, erec, M1, Q, hopwise, 3, M0, 0, out, n);
}

// Round 17
// 121.048 us; speedup vs baseline: 1.3170x; 1.0427x over previous
//
#include <hip/hip_runtime.h>
#include <hip/hip_bf16.h>

// MSTAGNN: N=10000, E=160000, HID=64, HEADS=8, D=8, KHOPS=3.
// R17 = exact R14 (best, 121.4us). R16 lesson: nt-STORE of kjn bypasses L2
// and forces the next kernel (hop0, launched immediately) to re-fetch 20.5MB
// from HBM -> +5us. nt-store is only right when the consumer is distant.
// Structure: erec int2 {j, norm_bits}; kjn = norm*relu(K[row]+ef) bf16
// streamed by hop0 (nt load ok: read-once); Vb bf16 table (1.28MB, L2)
// gathered per edge; M bf16 rows, one wave/node, f32 accum; qkv 4 nodes/
// thread (8 hits the VGPR cliff, R13); parallel CSR base alloc (fused
// deg+scan costs 49us in device fences, R15). No memsets (rocclr fill is
// ~40us each in-graph, R5). K-propagation in the reference is dead code.

#define HIDC 64
#define MELEMS 512  // HEADS * D * D

typedef float fx4 __attribute__((ext_vector_type(4)));

__device__ __forceinline__ unsigned bf16rne(float x) {
    unsigned u = __float_as_uint(x);
    return (u + 0x7FFFu + ((u >> 16) & 1u)) >> 16;
}
__device__ __forceinline__ unsigned pack2(float lo, float hi) {
    return bf16rne(lo) | (bf16rne(hi) << 16);
}
__device__ __forceinline__ float bfval(unsigned short v) {
    return __uint_as_float((unsigned)v << 16);
}
__device__ __forceinline__ void acc8(float* acc, float s, uint4 a) {
    acc[0] = fmaf(s, __uint_as_float(a.x << 16), acc[0]);
    acc[1] = fmaf(s, __uint_as_float(a.x & 0xFFFF0000u), acc[1]);
    acc[2] = fmaf(s, __uint_as_float(a.y << 16), acc[2]);
    acc[3] = fmaf(s, __uint_as_float(a.y & 0xFFFF0000u), acc[3]);
    acc[4] = fmaf(s, __uint_as_float(a.z << 16), acc[4]);
    acc[5] = fmaf(s, __uint_as_float(a.z & 0xFFFF0000u), acc[5]);
    acc[6] = fmaf(s, __uint_as_float(a.w << 16), acc[6]);
    acc[7] = fmaf(s, __uint_as_float(a.w & 0xFFFF0000u), acc[7]);
}

// Q,K = x@W + b (relu on Q); Vb = bf16(x@Wv+bv); out = hopwise[0]*V (full
// overwrite -> replay safe). 4 nodes/thread (VGPR ~100, good occupancy).
// Side jobs: zero deg[] and the CSR base counter.
__global__ __launch_bounds__(256) void qkv_kernel(
    const float* __restrict__ x,
    const float* __restrict__ Wq, const float* __restrict__ bq,
    const float* __restrict__ Wk, const float* __restrict__ bk,
    const float* __restrict__ Wv, const float* __restrict__ bv,
    const float* __restrict__ hopwise,
    float* __restrict__ Q, float* __restrict__ K,
    unsigned short* __restrict__ Vb,
    float* __restrict__ out, int* __restrict__ deg,
    int* __restrict__ counter, int n) {
    int gid = blockIdx.x * blockDim.x + threadIdx.x;
    if (gid < n) deg[gid] = 0;
    if (gid == 0) *counter = 0;
    int c = gid & 63;
    int nb = (gid >> 6) * 4;
    if (nb >= n) return;
    int mcnt = min(4, n - nb);
    float aq[4], ak[4], av[4];
    #pragma unroll
    for (int m = 0; m < 4; ++m) { aq[m] = bq[c]; ak[m] = bk[c]; av[m] = bv[c]; }
    const float4* x4 = (const float4*)x;
    for (int k4 = 0; k4 < 16; ++k4) {
        float4 xv[4];
        #pragma unroll
        for (int m = 0; m < 4; ++m)
            xv[m] = x4[(size_t)(nb + (m < mcnt ? m : 0)) * 16 + k4];
        #pragma unroll
        for (int kk = 0; kk < 4; ++kk) {
            int k = k4 * 4 + kk;
            float wq = Wq[k * HIDC + c], wk = Wk[k * HIDC + c], wv = Wv[k * HIDC + c];
            #pragma unroll
            for (int m = 0; m < 4; ++m) {
                float xvk = (kk == 0) ? xv[m].x : (kk == 1) ? xv[m].y
                          : (kk == 2) ? xv[m].z : xv[m].w;
                aq[m] = fmaf(xvk, wq, aq[m]);
                ak[m] = fmaf(xvk, wk, ak[m]);
                av[m] = fmaf(xvk, wv, av[m]);
            }
        }
    }
    #pragma unroll
    for (int m = 0; m < 4; ++m) {
        if (m < mcnt) {
            size_t idx = (size_t)(nb + m) * HIDC + c;
            Q[idx] = fmaxf(aq[m], 0.f);
            K[idx] = ak[m];
            Vb[idx] = (unsigned short)bf16rne(av[m]);
            out[idx] = hopwise[0] * av[m];
        }
    }
}

__global__ void deg_kernel(const int* __restrict__ col, int* __restrict__ deg, int e) {
    int i = blockIdx.x * blockDim.x + threadIdx.x;
    if (i < e) atomicAdd(&deg[col[i]], 1);
}

// parallel CSR base allocation: per-1024-node block scan + atomic block base.
// rowbeg[i] = cursor[i] = global slot base for node i (NOT globally monotone;
// hop kernels use end = rowbeg[n] + deg[n]).
__global__ __launch_bounds__(1024) void base_kernel(const int* __restrict__ deg,
                                                    int* __restrict__ counter,
                                                    int* __restrict__ rowbeg,
                                                    int* __restrict__ cursor, int n) {
    __shared__ int wsum[16];
    __shared__ int blockbase;
    int i = blockIdx.x * 1024 + threadIdx.x;
    int lane = threadIdx.x & 63, w = threadIdx.x >> 6;
    int v = (i < n) ? deg[i] : 0;
    int s = v;
    #pragma unroll
    for (int off = 1; off < 64; off <<= 1) {
        int t = __shfl_up(s, off);
        if (lane >= off) s += t;
    }
    if (lane == 63) wsum[w] = s;
    __syncthreads();
    if (threadIdx.x == 0) {
        int acc = 0;
        #pragma unroll
        for (int w2 = 0; w2 < 16; ++w2) { int t = wsum[w2]; wsum[w2] = acc; acc += t; }
        blockbase = atomicAdd(counter, acc);
    }
    __syncthreads();
    int excl = blockbase + wsum[w] + s - v;
    if (i < n) {
        rowbeg[i] = excl;
        cursor[i] = excl;
    }
}

// fused pos+stage: 16 threads/edge. Leader (c4==0) computes norm + CSR slot
// (atomic), writes erec[pos]={srcrow, norm_bits}, broadcasts {r,pos,nv};
// all 16 lanes stage kjn[pos] = nv*relu(K[r]+ef[i]) as 64 bf16 (128B row).
// ef read non-temporal (read-once); K gathers L2; kjn stored normally
// (consumed by the NEXT kernel -> keep it in L2; nt-store cost +5us, R16).
__global__ __launch_bounds__(256) void stage_kernel(
    const int* __restrict__ row, const int* __restrict__ col,
    const float* __restrict__ ew, const int* __restrict__ deg,
    int* __restrict__ cursor, int2* __restrict__ erec,
    const float* __restrict__ K, const float* __restrict__ ef,
    unsigned short* __restrict__ kjn, int e) {
    int gtid = blockIdx.x * blockDim.x + threadIdx.x;
    int i = gtid >> 4;
    if (i >= e) return;
    int c4 = gtid & 15;
    int lane = threadIdx.x & 63;
    int lb = lane & 48;  // leader lane of this 16-thread group
    int r = 0, pos = 0;
    float nv = 0.f;
    if (c4 == 0) {
        r = row[i];
        int cc = col[i];
        int dr = deg[r], dc = deg[cc];
        nv = ew[i];
        nv *= (dr > 0) ? rsqrtf((float)dr) : 0.f;
        nv *= (dc > 0) ? rsqrtf((float)dc) : 0.f;
        pos = atomicAdd(&cursor[cc], 1);
        erec[pos] = make_int2(r, __float_as_int(nv));
    }
    r = __shfl(r, lb);
    pos = __shfl(pos, lb);
    nv = __shfl(nv, lb);
    const fx4* efv = (const fx4*)ef;
    const float4* Kv = (const float4*)K;
    fx4 f = __builtin_nontemporal_load(&efv[(size_t)i * 16 + c4]);
    float4 kk = Kv[(size_t)r * 16 + c4];
    uint2 kjp;
    kjp.x = pack2(nv * fmaxf(kk.x + f.x, 0.f), nv * fmaxf(kk.y + f.y, 0.f));
    kjp.y = pack2(nv * fmaxf(kk.z + f.z, 0.f), nv * fmaxf(kk.w + f.w, 0.f));
    ((uint2*)(kjn + (size_t)pos * 64))[c4] = kjp;
}

// epilogue (64 threads/node, t = h*8+ii owns M[h][ii][0..7]):
// H = Q.M (reduce ii via xor 1/2/4), clamp-norm (j-reduce in-thread)
__device__ __forceinline__ void epilogue64(const float* acc, const float* __restrict__ Q,
                                           float hw, int n, int h, int ii,
                                           float* __restrict__ out) {
    float q = Q[n * HIDC + h * 8 + ii];
    float p[8];
    #pragma unroll
    for (int j = 0; j < 8; ++j) p[j] = q * acc[j];
    #pragma unroll
    for (int off = 1; off < 8; off <<= 1) {
        #pragma unroll
        for (int j = 0; j < 8; ++j) p[j] += __shfl_xor(p[j], off);
    }
    float ssq = 0.f;
    #pragma unroll
    for (int j = 0; j < 8; ++j) ssq = fmaf(p[j], p[j], ssq);
    float nr = sqrtf(ssq * 0.125f);
    float sc = (nr > 1.f) ? (hw / nr) : hw;
    if (ii == 0) {
        float4* o = (float4*)(out + (size_t)n * HIDC + h * 8);
        float4 c0 = o[0], c1 = o[1];
        c0.x = fmaf(p[0], sc, c0.x); c0.y = fmaf(p[1], sc, c0.y);
        c0.z = fmaf(p[2], sc, c0.z); c0.w = fmaf(p[3], sc, c0.w);
        c1.x = fmaf(p[4], sc, c1.x); c1.y = fmaf(p[5], sc, c1.y);
        c1.z = fmaf(p[6], sc, c1.z); c1.w = fmaf(p[7], sc, c1.w);
        o[0] = c0; o[1] = c1;
    }
}

// hop 0: one wave per node; kjn streamed sequentially (nt load: read-once),
// V gathered from the 1.28MB L2-resident bf16 table. Unroll 4.
__global__ __launch_bounds__(256) void hop0_kernel(
    const int* __restrict__ rowbeg, const int* __restrict__ deg,
    const int2* __restrict__ erec, const unsigned short* __restrict__ kjn,
    const unsigned short* __restrict__ Vb,
    const float* __restrict__ Q, const float* __restrict__ hopwise,
    unsigned short* __restrict__ M0, float* __restrict__ out, int nn) {
    int n = blockIdx.x * 4 + (threadIdx.x >> 6);
    if (n >= nn) return;
    int t = threadIdx.x & 63;
    int h = t >> 3, ii = t & 7;
    int beg = rowbeg[n], end = beg + deg[n];
    float acc[8] = {0, 0, 0, 0, 0, 0, 0, 0};
    int k = beg;
    for (; k + 4 <= end; k += 4) {
        int j0 = erec[k].x,     j1 = erec[k + 1].x;
        int j2 = erec[k + 2].x, j3 = erec[k + 3].x;
        float s0 = bfval(__builtin_nontemporal_load(&kjn[(size_t)(k)     * 64 + t]));
        float s1 = bfval(__builtin_nontemporal_load(&kjn[(size_t)(k + 1) * 64 + t]));
        float s2 = bfval(__builtin_nontemporal_load(&kjn[(size_t)(k + 2) * 64 + t]));
        float s3 = bfval(__builtin_nontemporal_load(&kjn[(size_t)(k + 3) * 64 + t]));
        uint4 v0 = *(const uint4*)(Vb + (size_t)j0 * 64 + h * 8);
        uint4 v1 = *(const uint4*)(Vb + (size_t)j1 * 64 + h * 8);
        uint4 v2 = *(const uint4*)(Vb + (size_t)j2 * 64 + h * 8);
        uint4 v3 = *(const uint4*)(Vb + (size_t)j3 * 64 + h * 8);
        acc8(acc, s0, v0);
        acc8(acc, s1, v1);
        acc8(acc, s2, v2);
        acc8(acc, s3, v3);
    }
    for (; k < end; ++k) {
        float s = bfval(__builtin_nontemporal_load(&kjn[(size_t)k * 64 + t]));
        uint4 v = *(const uint4*)(Vb + (size_t)erec[k].x * 64 + h * 8);
        acc8(acc, s, v);
    }
    uint4 st;
    st.x = pack2(acc[0], acc[1]); st.y = pack2(acc[2], acc[3]);
    st.z = pack2(acc[4], acc[5]); st.w = pack2(acc[6], acc[7]);
    ((uint4*)M0)[(size_t)n * 64 + t] = st;
    epilogue64(acc, Q, hopwise[1], n, h, ii, out);
}

// hop k>=1: Mout[n] = sum_e norm * Min[row[e]]; one wave per node, bf16 rows,
// unroll 8 (8 uint4 row-gathers in flight).
__global__ __launch_bounds__(256) void hopk_kernel(
    const int* __restrict__ rowbeg, const int* __restrict__ deg,
    const int2* __restrict__ erec,
    const unsigned short* __restrict__ Min, const float* __restrict__ Q,
    const float* __restrict__ hopwise, int hopidx,
    unsigned short* __restrict__ Mout, int writeM, float* __restrict__ out, int nn) {
    int n = blockIdx.x * 4 + (threadIdx.x >> 6);
    if (n >= nn) return;
    int t = threadIdx.x & 63;
    int beg = rowbeg[n], end = beg + deg[n];
    float acc[8] = {0, 0, 0, 0, 0, 0, 0, 0};
    const uint4* Mv = (const uint4*)Min;  // row j at Mv[j*64 + t]
    int k = beg;
    for (; k + 8 <= end; k += 8) {
        int2 e0 = erec[k],     e1 = erec[k + 1], e2 = erec[k + 2], e3 = erec[k + 3];
        int2 e4 = erec[k + 4], e5 = erec[k + 5], e6 = erec[k + 6], e7 = erec[k + 7];
        uint4 a0 = Mv[(size_t)e0.x * 64 + t];
        uint4 a1 = Mv[(size_t)e1.x * 64 + t];
        uint4 a2 = Mv[(size_t)e2.x * 64 + t];
        uint4 a3 = Mv[(size_t)e3.x * 64 + t];
        uint4 a4 = Mv[(size_t)e4.x * 64 + t];
        uint4 a5 = Mv[(size_t)e5.x * 64 + t];
        uint4 a6 = Mv[(size_t)e6.x * 64 + t];
        uint4 a7 = Mv[(size_t)e7.x * 64 + t];
        acc8(acc, __int_as_float(e0.y), a0);
        acc8(acc, __int_as_float(e1.y), a1);
        acc8(acc, __int_as_float(e2.y), a2);
        acc8(acc, __int_as_float(e3.y), a3);
        acc8(acc, __int_as_float(e4.y), a4);
        acc8(acc, __int_as_float(e5.y), a5);
        acc8(acc, __int_as_float(e6.y), a6);
        acc8(acc, __int_as_float(e7.y), a7);
    }
    for (; k + 4 <= end; k += 4) {
        int2 e0 = erec[k], e1 = erec[k + 1], e2 = erec[k + 2], e3 = erec[k + 3];
        uint4 a0 = Mv[(size_t)e0.x * 64 + t];
        uint4 a1 = Mv[(size_t)e1.x * 64 + t];
        uint4 a2 = Mv[(size_t)e2.x * 64 + t];
        uint4 a3 = Mv[(size_t)e3.x * 64 + t];
        acc8(acc, __int_as_float(e0.y), a0);
        acc8(acc, __int_as_float(e1.y), a1);
        acc8(acc, __int_as_float(e2.y), a2);
        acc8(acc, __int_as_float(e3.y), a3);
    }
    for (; k < end; ++k) {
        int2 e0 = erec[k];
        acc8(acc, __int_as_float(e0.y), Mv[(size_t)e0.x * 64 + t]);
    }
    if (writeM) {
        uint4 st;
        st.x = pack2(acc[0], acc[1]); st.y = pack2(acc[2], acc[3]);
        st.z = pack2(acc[4], acc[5]); st.w = pack2(acc[6], acc[7]);
        ((uint4*)Mout)[(size_t)n * 64 + t] = st;
    }
    int h = t >> 3, ii = t & 7;
    epilogue64(acc, Q, hopwise[hopidx], n, h, ii, out);
}

extern "C" void kernel_launch(void* const* d_in, const int* in_sizes, int n_in,
                              void* d_out, int out_size, void* d_ws, size_t ws_size,
                              hipStream_t stream) {
    const float* x       = (const float*)d_in[0];
    const int*   ei      = (const int*)d_in[1];
    const float* ef      = (const float*)d_in[2];
    const float* ew      = (const float*)d_in[3];
    const float* Wq      = (const float*)d_in[4];
    const float* bq      = (const float*)d_in[5];
    const float* Wk      = (const float*)d_in[6];
    const float* bk      = (const float*)d_in[7];
    const float* Wv      = (const float*)d_in[8];
    const float* bv      = (const float*)d_in[9];
    const float* hopwise = (const float*)d_in[10];
    float* out = (float*)d_out;

    const int n = in_sizes[0] / HIDC;   // 10000
    const int e = in_sizes[1] / 2;      // 160000
    const int* row = ei;
    const int* col = ei + e;

    char* base = (char*)d_ws;
    size_t off = 0;
    auto alloc = [&](size_t bytes) -> void* {
        void* p = base + off;
        off = (off + bytes + 255) & ~(size_t)255;
        return p;
    };
    int*            deg     = (int*)           alloc((size_t)n * 4);
    int*            cursor  = (int*)           alloc((size_t)n * 4);
    int*            rowbeg  = (int*)           alloc((size_t)n * 4);
    int*            counter = (int*)           alloc(256);
    int2*           erec    = (int2*)          alloc((size_t)e * 8);
    unsigned short* kjn     = (unsigned short*)alloc((size_t)e * HIDC * 2);
    float*          Q       = (float*)         alloc((size_t)n * HIDC * 4);
    float*          K       = (float*)         alloc((size_t)n * HIDC * 4);
    unsigned short* Vb      = (unsigned short*)alloc((size_t)n * HIDC * 2);
    unsigned short* M0      = (unsigned short*)alloc((size_t)n * MELEMS * 2);
    unsigned short* M1      = (unsigned short*)alloc((size_t)n * MELEMS * 2);
    (void)ws_size;

    // 4 nodes/thread-column: (n/4) waves of 64
    int qthreads = ((n + 3) / 4) * 64;
    int qb = (qthreads + 255) / 256;
    qkv_kernel<<<qb, 256, 0, stream>>>(x, Wq, bq, Wk, bk, Wv, bv, hopwise,
                                       Q, K, Vb, out, deg, counter, n);

    int eb = (e + 255) / 256;
    deg_kernel<<<eb, 256, 0, stream>>>(col, deg, e);

    int bb = (n + 1023) / 1024;
    base_kernel<<<bb, 1024, 0, stream>>>(deg, counter, rowbeg, cursor, n);

    int sb = ((e * 16) + 255) / 256;
    stage_kernel<<<sb, 256, 0, stream>>>(row, col, ew, deg, cursor,
                                         erec, K, ef, kjn, e);

    int nb = (n + 3) / 4;
    hop0_kernel<<<nb, 256, 0, stream>>>(rowbeg, deg, erec, kjn, Vb, Q,
                                        hopwise, M0, out, n);
    hopk_kernel<<<nb, 256, 0, stream>>>(rowbeg, deg, erec, M0, Q, hopwise, 2, M1, 1, out, n);
    hopk_kernel<<<nb, 256, 0, stream>>>(rowbeg, deg, erec, M1, Q, hopwise, 3, M0, 0, out, n);
}